// Round 3
// baseline (78.799 us; speedup 1.0000x reference)
//
#include <hip/hip_runtime.h>

// Problem constants (match reference file).
#define M_ROWS 200000
#define D_DIM  256
#define NB     1024          // pass-1 blocks
#define TPB    512           // threads per block (8 waves)
#define WPB    (TPB / 64)    // waves per block
#define TOTAL_WAVES (NB * WPB)   // 8192 = 100% of 256 CU * 32 waves
#define ROWS   4             // rows per wave per iteration (ILP)

// Pass 1: each wave processes ROWS rows per iteration. Lane l holds
// u[4l..4l+3] in regs. Per row: coalesced float4 load of keys row,
// 4 interleaved 64-lane butterfly reductions (ILP hides shuffle latency),
// exp, accumulate r * values row into per-lane float4 accumulator.
// Block-reduce 8 waves via LDS; write 256-float partial column-major.
__global__ __launch_bounds__(TPB) void iv_pass1(
    const float* __restrict__ u,
    const float4* __restrict__ keys4,
    const float4* __restrict__ values4,
    float* __restrict__ partial)   // layout: partial[col * NB + block]
{
    const int lane  = threadIdx.x & 63;
    const int wid   = threadIdx.x >> 6;
    const int gwave = blockIdx.x * WPB + wid;

    const float4 u4 = ((const float4*)u)[lane];

    float4 acc = make_float4(0.f, 0.f, 0.f, 0.f);

    // Chunks of ROWS rows; 200000 % 4 == 0 and chunks are 4-aligned,
    // so every in-range chunk is full (no sub-chunk tail).
    for (int row = gwave * ROWS; row + ROWS <= M_ROWS; row += TOTAL_WAVES * ROWS) {
        const float4 k0 = keys4[(row + 0) * 64 + lane];
        const float4 k1 = keys4[(row + 1) * 64 + lane];
        const float4 k2 = keys4[(row + 2) * 64 + lane];
        const float4 k3 = keys4[(row + 3) * 64 + lane];

        float p0 = k0.x * u4.x + k0.y * u4.y + k0.z * u4.z + k0.w * u4.w;
        float p1 = k1.x * u4.x + k1.y * u4.y + k1.z * u4.z + k1.w * u4.w;
        float p2 = k2.x * u4.x + k2.y * u4.y + k2.z * u4.z + k2.w * u4.w;
        float p3 = k3.x * u4.x + k3.y * u4.y + k3.z * u4.z + k3.w * u4.w;

        // Issue value loads early so they overlap the shuffle chains.
        const float4 v0 = values4[(row + 0) * 64 + lane];
        const float4 v1 = values4[(row + 1) * 64 + lane];
        const float4 v2 = values4[(row + 2) * 64 + lane];
        const float4 v3 = values4[(row + 3) * 64 + lane];

        // Four independent butterfly chains, interleaved for ILP.
        #pragma unroll
        for (int m = 32; m >= 1; m >>= 1) {
            p0 += __shfl_xor(p0, m, 64);
            p1 += __shfl_xor(p1, m, 64);
            p2 += __shfl_xor(p2, m, 64);
            p3 += __shfl_xor(p3, m, 64);
        }

        const float r0 = __expf(p0);
        const float r1 = __expf(p1);
        const float r2 = __expf(p2);
        const float r3 = __expf(p3);

        acc.x += r0 * v0.x + r1 * v1.x + r2 * v2.x + r3 * v3.x;
        acc.y += r0 * v0.y + r1 * v1.y + r2 * v2.y + r3 * v3.y;
        acc.z += r0 * v0.z + r1 * v1.z + r2 * v2.z + r3 * v3.z;
        acc.w += r0 * v0.w + r1 * v1.w + r2 * v2.w + r3 * v3.w;
    }

    // Block reduction across the 8 waves. Lane l of wave w holds cols 4l..4l+3.
    __shared__ float lds[WPB][D_DIM];
    *(float4*)&lds[wid][lane * 4] = acc;
    __syncthreads();

    const int t = threadIdx.x;
    if (t < D_DIM) {
        float s = 0.f;
        #pragma unroll
        for (int w = 0; w < WPB; ++w) s += lds[w][t];
        // Column-major so pass 2 reads each column's partials contiguously.
        partial[t * NB + blockIdx.x] = s;
    }
}

// Pass 2: block c sums its 1024 partials (contiguous, L2-resident),
// writes out[256+c]; also passes through out[c] = u[c].
__global__ __launch_bounds__(256) void iv_pass2(
    const float* __restrict__ partial,
    const float* __restrict__ u,
    float* __restrict__ out)
{
    const int c = blockIdx.x;
    const int t = threadIdx.x;

    float s = 0.f;
    #pragma unroll
    for (int i = 0; i < NB / 256; ++i)
        s += partial[c * NB + i * 256 + t];

    #pragma unroll
    for (int m = 32; m >= 1; m >>= 1)
        s += __shfl_xor(s, m, 64);

    __shared__ float lds[256 / 64];
    if ((t & 63) == 0) lds[t >> 6] = s;
    __syncthreads();

    if (t == 0) {
        out[D_DIM + c] = lds[0] + lds[1] + lds[2] + lds[3];
        out[c] = u[c];
    }
}

extern "C" void kernel_launch(void* const* d_in, const int* in_sizes, int n_in,
                              void* d_out, int out_size, void* d_ws, size_t ws_size,
                              hipStream_t stream) {
    const float* u      = (const float*)d_in[0];   // (256,)
    const float* keys   = (const float*)d_in[1];   // (200000, 256)
    const float* values = (const float*)d_in[2];   // (200000, 256)
    float* out = (float*)d_out;                    // 512 floats: [u ; u_]
    float* partial = (float*)d_ws;                 // needs NB*256*4 = 1 MB

    iv_pass1<<<NB, TPB, 0, stream>>>(u, (const float4*)keys,
                                     (const float4*)values, partial);
    iv_pass2<<<D_DIM, 256, 0, stream>>>(partial, u, out);
}

// Round 4
// 78.216 us; speedup vs baseline: 1.0075x; 1.0075x over previous
//
#include <hip/hip_runtime.h>

// Problem constants (match reference file).
#define M_ROWS 200000
#define D_DIM  256
#define NB     1024          // pass-1 blocks
#define TPB    512           // threads per block (8 waves)
#define WPB    (TPB / 64)    // waves per block
#define TOTAL_WAVES (NB * WPB)   // 8192 = 100% of 256 CU * 32 wave slots
#define ROWS   2             // rows per wave per iteration (k+v both in flight)

// Pass 1: each wave processes ROWS rows per iteration. Lane l holds
// u[4l..4l+3] in regs. All k and v loads for the iteration are issued
// before any use (fits in ~32 VGPR -> still 8 waves/SIMD), two
// interleaved 64-lane butterfly reductions, exp, weighted accumulate.
// Block-reduce 8 waves via LDS; write 256-float partial column-major.
__global__ __launch_bounds__(TPB) void iv_pass1(
    const float* __restrict__ u,
    const float4* __restrict__ keys4,
    const float4* __restrict__ values4,
    float* __restrict__ partial)   // layout: partial[col * NB + block]
{
    const int lane  = threadIdx.x & 63;
    const int wid   = threadIdx.x >> 6;
    const int gwave = blockIdx.x * WPB + wid;

    const float4 u4 = ((const float4*)u)[lane];

    float4 acc = make_float4(0.f, 0.f, 0.f, 0.f);

    // Chunks of ROWS rows; M_ROWS % 2 == 0 so every in-range chunk is full.
    for (int row = gwave * ROWS; row + ROWS <= M_ROWS; row += TOTAL_WAVES * ROWS) {
        // Issue all 4 loads up front so both streams are in flight together.
        const float4 k0 = keys4[(row + 0) * 64 + lane];
        const float4 k1 = keys4[(row + 1) * 64 + lane];
        const float4 v0 = values4[(row + 0) * 64 + lane];
        const float4 v1 = values4[(row + 1) * 64 + lane];

        float p0 = k0.x * u4.x + k0.y * u4.y + k0.z * u4.z + k0.w * u4.w;
        float p1 = k1.x * u4.x + k1.y * u4.y + k1.z * u4.z + k1.w * u4.w;

        // Two independent butterfly chains, interleaved for ILP.
        #pragma unroll
        for (int m = 32; m >= 1; m >>= 1) {
            p0 += __shfl_xor(p0, m, 64);
            p1 += __shfl_xor(p1, m, 64);
        }

        const float r0 = __expf(p0);
        const float r1 = __expf(p1);

        acc.x += r0 * v0.x + r1 * v1.x;
        acc.y += r0 * v0.y + r1 * v1.y;
        acc.z += r0 * v0.z + r1 * v1.z;
        acc.w += r0 * v0.w + r1 * v1.w;
    }

    // Block reduction across the 8 waves. Lane l of wave w holds cols 4l..4l+3.
    __shared__ float lds[WPB][D_DIM];
    *(float4*)&lds[wid][lane * 4] = acc;
    __syncthreads();

    const int t = threadIdx.x;
    if (t < D_DIM) {
        float s = 0.f;
        #pragma unroll
        for (int w = 0; w < WPB; ++w) s += lds[w][t];
        // Column-major so pass 2 reads each column's partials contiguously.
        partial[t * NB + blockIdx.x] = s;
    }
}

// Pass 2: block c sums its 1024 partials (contiguous, L2/L3-resident),
// writes out[256+c]; also passes through out[c] = u[c].
__global__ __launch_bounds__(256) void iv_pass2(
    const float* __restrict__ partial,
    const float* __restrict__ u,
    float* __restrict__ out)
{
    const int c = blockIdx.x;
    const int t = threadIdx.x;

    float s = 0.f;
    #pragma unroll
    for (int i = 0; i < NB / 256; ++i)
        s += partial[c * NB + i * 256 + t];

    #pragma unroll
    for (int m = 32; m >= 1; m >>= 1)
        s += __shfl_xor(s, m, 64);

    __shared__ float lds[256 / 64];
    if ((t & 63) == 0) lds[t >> 6] = s;
    __syncthreads();

    if (t == 0) {
        out[D_DIM + c] = lds[0] + lds[1] + lds[2] + lds[3];
        out[c] = u[c];
    }
}

extern "C" void kernel_launch(void* const* d_in, const int* in_sizes, int n_in,
                              void* d_out, int out_size, void* d_ws, size_t ws_size,
                              hipStream_t stream) {
    const float* u      = (const float*)d_in[0];   // (256,)
    const float* keys   = (const float*)d_in[1];   // (200000, 256)
    const float* values = (const float*)d_in[2];   // (200000, 256)
    float* out = (float*)d_out;                    // 512 floats: [u ; u_]
    float* partial = (float*)d_ws;                 // needs NB*256*4 = 1 MB

    iv_pass1<<<NB, TPB, 0, stream>>>(u, (const float4*)keys,
                                     (const float4*)values, partial);
    iv_pass2<<<D_DIM, 256, 0, stream>>>(partial, u, out);
}